// Round 1
// baseline (706.958 us; speedup 1.0000x reference)
//
#include <hip/hip_runtime.h>
#include <math.h>

#define B 32
#define T 2048
#define H 512

#define BT 64
#define BO 64
#define BK 16

// ---------------- K1: q-projection + bias; zero score-accumulator and context out
__global__ __launch_bounds__(256) void k1_init(const float* __restrict__ query,
                                               const float* __restrict__ q_w,
                                               const float* __restrict__ bias,
                                               float* __restrict__ qpb,
                                               float* __restrict__ pre,
                                               float* __restrict__ ctx_out) {
    __shared__ float qs[H];
    const int b = blockIdx.x;
    const int tid = threadIdx.x;
    for (int i = tid; i < H; i += 256) qs[i] = query[b * H + i];
    // zero pre-activation accumulator (B*T) and context output (B*H)
    for (int i = tid; i < T; i += 256) pre[b * T + i] = 0.f;
    for (int i = tid; i < H; i += 256) ctx_out[b * H + i] = 0.f;
    __syncthreads();
    for (int o = tid; o < H; o += 256) {
        const float* wr = q_w + (size_t)o * H;
        float acc = 0.f;
#pragma unroll 8
        for (int h = 0; h < H; ++h) acc += qs[h] * wr[h];
        qpb[b * H + o] = acc + bias[o];
    }
}

// ---------------- K2: fused v-projection GEMM + conv + tanh + score partial reduction
__global__ __launch_bounds__(256) void k2_score(const float* __restrict__ value,
                                                const float* __restrict__ v_w,
                                                const float* __restrict__ la,
                                                const float* __restrict__ conv_w,
                                                const float* __restrict__ conv_b,
                                                const float* __restrict__ s_w,
                                                const float* __restrict__ qpb,
                                                float* __restrict__ pre) {
    __shared__ float As[BK][BT];   // value tile, [k][t]
    __shared__ float Ws[BK][BO];   // v_w tile,  [k][o]
    __shared__ float qpbs[BO], sws[BO], cbs[BO], cw0s[BO], cw1s[BO], cw2s[BO];
    __shared__ float las[BT + 2];

    const int t0 = blockIdx.x * BT;
    const int o0 = blockIdx.y * BO;
    const int b  = blockIdx.z;
    const int tid = threadIdx.x;
    const int tx = tid & 15;   // o micro-index
    const int ty = tid >> 4;   // t micro-index

    // stage epilogue constants
    if (tid < BO) {
        const int o = o0 + tid;
        qpbs[tid] = qpb[b * H + o];
        sws[tid]  = s_w[o];
        cbs[tid]  = conv_b[o];
        cw0s[tid] = conv_w[o * 3 + 0];
        cw1s[tid] = conv_w[o * 3 + 1];
        cw2s[tid] = conv_w[o * 3 + 2];
    } else if (tid < BO + BT + 2) {
        const int i = tid - BO;       // 0..65 -> la[b, t0-1 .. t0+BT]
        const int t = t0 + i - 1;
        las[i] = (t >= 0 && t < T) ? la[b * T + t] : 0.f;
    }

    float c[4][4];
#pragma unroll
    for (int i = 0; i < 4; ++i)
#pragma unroll
        for (int j = 0; j < 4; ++j) c[i][j] = 0.f;

    const float* vbase = value + (size_t)b * T * H;
    const int lt = tid >> 2;          // 0..63 (row within tile)
    const int lk = (tid & 3) * 4;     // 0,4,8,12 (k within chunk)

    for (int kc = 0; kc < H; kc += BK) {
        __syncthreads();
        float4 av = *(const float4*)(vbase + (size_t)(t0 + lt) * H + kc + lk);
        float4 wv = *(const float4*)(v_w + (size_t)(o0 + lt) * H + kc + lk);
        As[lk + 0][lt] = av.x; As[lk + 1][lt] = av.y;
        As[lk + 2][lt] = av.z; As[lk + 3][lt] = av.w;
        Ws[lk + 0][lt] = wv.x; Ws[lk + 1][lt] = wv.y;
        Ws[lk + 2][lt] = wv.z; Ws[lk + 3][lt] = wv.w;
        __syncthreads();
#pragma unroll
        for (int k = 0; k < BK; ++k) {
            const float4 a = *(const float4*)&As[k][ty * 4];
            const float4 w = *(const float4*)&Ws[k][tx * 4];
            c[0][0] += a.x * w.x; c[0][1] += a.x * w.y; c[0][2] += a.x * w.z; c[0][3] += a.x * w.w;
            c[1][0] += a.y * w.x; c[1][1] += a.y * w.y; c[1][2] += a.y * w.z; c[1][3] += a.y * w.w;
            c[2][0] += a.z * w.x; c[2][1] += a.z * w.y; c[2][2] += a.z * w.z; c[2][3] += a.z * w.w;
            c[3][0] += a.w * w.x; c[3][1] += a.w * w.y; c[3][2] += a.w * w.z; c[3][3] += a.w * w.w;
        }
    }

    // epilogue: e = tanh(v + qpb + conv); partial score = sum_o s_w[o]*e
    float part[4] = {0.f, 0.f, 0.f, 0.f};
#pragma unroll
    for (int i = 0; i < 4; ++i) {
        const int tl = ty * 4 + i;
#pragma unroll
        for (int j = 0; j < 4; ++j) {
            const int ol = tx * 4 + j;
            const float conv = cw0s[ol] * las[tl] + cw1s[ol] * las[tl + 1] +
                               cw2s[ol] * las[tl + 2] + cbs[ol];
            const float x = c[i][j] + qpbs[ol] + conv;
            part[i] += sws[ol] * tanhf(x);
        }
    }
    // reduce across tx (16 contiguous lanes within the wave)
#pragma unroll
    for (int i = 0; i < 4; ++i) {
        float v = part[i];
        v += __shfl_xor(v, 1);
        v += __shfl_xor(v, 2);
        v += __shfl_xor(v, 4);
        v += __shfl_xor(v, 8);
        if (tx == 0) atomicAdd(&pre[b * T + t0 + ty * 4 + i], v);
    }
}

// ---------------- K3a: sigmoid + L1 normalize -> attn
__global__ __launch_bounds__(256) void k3a_norm(const float* __restrict__ pre,
                                                const float* __restrict__ s_b,
                                                float* __restrict__ attn_out) {
    const int b = blockIdx.x;
    const int tid = threadIdx.x;
    const float sb = s_b[0];
    float s[8];
    float loc = 0.f;
#pragma unroll
    for (int i = 0; i < 8; ++i) {
        const float p = pre[b * T + tid + i * 256] + sb;
        const float sg = 1.f / (1.f + expf(-p));
        s[i] = sg;
        loc += sg;
    }
    __shared__ float red[4];
#pragma unroll
    for (int m = 1; m < 64; m <<= 1) loc += __shfl_xor(loc, m);
    if ((tid & 63) == 0) red[tid >> 6] = loc;
    __syncthreads();
    const float inv = 1.f / (red[0] + red[1] + red[2] + red[3]);
#pragma unroll
    for (int i = 0; i < 8; ++i) attn_out[b * T + tid + i * 256] = s[i] * inv;
}

// ---------------- K3b: context = sum_t attn[t] * value[t,:]
__global__ __launch_bounds__(256) void k3b_ctx(const float* __restrict__ value,
                                               const float* __restrict__ attn,
                                               float* __restrict__ ctx) {
    const int b = blockIdx.x;
    const int slice = blockIdx.y;   // 8 slices of 256 t
    const int tid = threadIdx.x;
    const float* vb = value + (size_t)b * T * H;
    float a0 = 0.f, a1 = 0.f;
    const int tbeg = slice * 256;
    for (int t = tbeg; t < tbeg + 256; ++t) {
        const float a = attn[b * T + t];
        a0 += a * vb[(size_t)t * H + tid];
        a1 += a * vb[(size_t)t * H + tid + 256];
    }
    atomicAdd(&ctx[b * H + tid], a0);
    atomicAdd(&ctx[b * H + tid + 256], a1);
}

extern "C" void kernel_launch(void* const* d_in, const int* in_sizes, int n_in,
                              void* d_out, int out_size, void* d_ws, size_t ws_size,
                              hipStream_t stream) {
    const float* query  = (const float*)d_in[0];
    const float* value  = (const float*)d_in[1];
    const float* la     = (const float*)d_in[2];
    const float* conv_w = (const float*)d_in[3];
    const float* conv_b = (const float*)d_in[4];
    const float* q_w    = (const float*)d_in[5];
    const float* v_w    = (const float*)d_in[6];
    const float* s_w    = (const float*)d_in[7];
    const float* s_b    = (const float*)d_in[8];
    const float* bias   = (const float*)d_in[9];

    float* out  = (float*)d_out;
    float* ctx  = out;            // (B, H)
    float* attn = out + B * H;    // (B, T)

    float* qpb = (float*)d_ws;    // B*H
    float* pre = qpb + B * H;     // B*T

    k1_init<<<B, 256, 0, stream>>>(query, q_w, bias, qpb, pre, ctx);

    dim3 g2(T / BT, H / BO, B);
    k2_score<<<g2, 256, 0, stream>>>(value, v_w, la, conv_w, conv_b, s_w, qpb, pre);

    k3a_norm<<<B, 256, 0, stream>>>(pre, s_b, attn);

    dim3 g3(B, 8);
    k3b_ctx<<<g3, 256, 0, stream>>>(value, attn, ctx);
}

// Round 2
// 367.241 us; speedup vs baseline: 1.9251x; 1.9251x over previous
//
#include <hip/hip_runtime.h>
#include <math.h>

#define B 32
#define T 2048
#define H 512

#define BM 128
#define BN 128
// K chunk = 32

typedef __attribute__((ext_vector_type(8))) __bf16 bf16x8;
typedef __attribute__((ext_vector_type(4))) float floatx4;

static __device__ __forceinline__ unsigned short f2bf(float f) {
    union { float f; unsigned int u; } v; v.f = f;
    unsigned int r = v.u + 0x7fffu + ((v.u >> 16) & 1u);   // RNE
    return (unsigned short)(r >> 16);
}

static __device__ __forceinline__ float fast_tanh(float x) {
    float ex = __expf(2.f * x);
    return 1.f - 2.f * __builtin_amdgcn_rcpf(ex + 1.f);
}

// ---------------- K1: q-projection + bias; zero score-accumulator and context out
__global__ __launch_bounds__(256) void k1_init(const float* __restrict__ query,
                                               const float* __restrict__ q_w,
                                               const float* __restrict__ bias,
                                               float* __restrict__ qpb,
                                               float* __restrict__ pre,
                                               float* __restrict__ ctx_out) {
    __shared__ float qs[H];
    const int b = blockIdx.x;
    const int tid = threadIdx.x;
    for (int i = tid; i < H; i += 256) qs[i] = query[b * H + i];
    for (int i = tid; i < T; i += 256) pre[b * T + i] = 0.f;
    for (int i = tid; i < H; i += 256) ctx_out[b * H + i] = 0.f;
    __syncthreads();
    for (int o = tid; o < H; o += 256) {
        const float* wr = q_w + (size_t)o * H;
        float acc = 0.f;
#pragma unroll 8
        for (int h = 0; h < H; ++h) acc += qs[h] * wr[h];
        qpb[b * H + o] = acc + bias[o];
    }
}

// ---------------- K2: bf16 MFMA v-projection + fused conv/tanh/score epilogue
__global__ __launch_bounds__(256) void k2_score_mfma(const float* __restrict__ value,
                                                     const float* __restrict__ v_w,
                                                     const float* __restrict__ la,
                                                     const float* __restrict__ conv_w,
                                                     const float* __restrict__ conv_b,
                                                     const float* __restrict__ s_w,
                                                     const float* __restrict__ qpb,
                                                     float* __restrict__ pre) {
    __shared__ unsigned short As[BM][40];   // padded stride: 40 bf16 = 80 B -> 2-way free
    __shared__ unsigned short Bs[BN][40];
    __shared__ float qpbs[BN], sws[BN], cbs[BN], cw0s[BN], cw1s[BN], cw2s[BN];
    __shared__ float las[BM + 2];

    const int t0 = blockIdx.x * BM;
    const int o0 = blockIdx.y * BN;
    const int b  = blockIdx.z;
    const int tid = threadIdx.x;
    const int wave = tid >> 6;
    const int lane = tid & 63;
    const int tx   = lane & 15;
    const int quad = lane >> 4;
    const int wm = (wave >> 1) * 64;   // wave's t-offset within tile
    const int wn = (wave & 1) * 64;    // wave's o-offset within tile

    if (tid < BN) {
        const int o = o0 + tid;
        qpbs[tid] = qpb[b * H + o];
        sws[tid]  = s_w[o];
        cbs[tid]  = conv_b[o];
        cw0s[tid] = conv_w[o * 3 + 0];
        cw1s[tid] = conv_w[o * 3 + 1];
        cw2s[tid] = conv_w[o * 3 + 2];
    }
    if (tid < BM + 2) {
        const int t = t0 + tid - 1;
        las[tid] = (t >= 0 && t < T) ? la[b * T + t] : 0.f;
    }

    floatx4 acc[4][4];
#pragma unroll
    for (int i = 0; i < 4; ++i)
#pragma unroll
        for (int j = 0; j < 4; ++j) acc[i][j] = (floatx4){0.f, 0.f, 0.f, 0.f};

    const float* vbase = value + (size_t)b * T * H;

    // staging assignment: chunk id = l*256+tid; row = id>>2 (0..127), k8 = (id&3)*8
    const int r0 = tid >> 2;          // rows 0..63   (l=0)
    const int r1 = 64 + (tid >> 2);   // rows 64..127 (l=1)
    const int k8 = (tid & 3) * 8;

    for (int kc = 0; kc < H; kc += 32) {
        // issue global loads (fp32), 8 floats per chunk
        const float* ga0 = vbase + (size_t)(t0 + r0) * H + kc + k8;
        const float* ga1 = vbase + (size_t)(t0 + r1) * H + kc + k8;
        const float* gb0 = v_w + (size_t)(o0 + r0) * H + kc + k8;
        const float* gb1 = v_w + (size_t)(o0 + r1) * H + kc + k8;
        float4 a00 = *(const float4*)ga0, a01 = *(const float4*)(ga0 + 4);
        float4 a10 = *(const float4*)ga1, a11 = *(const float4*)(ga1 + 4);
        float4 b00 = *(const float4*)gb0, b01 = *(const float4*)(gb0 + 4);
        float4 b10 = *(const float4*)gb1, b11 = *(const float4*)(gb1 + 4);

        __syncthreads();   // previous iter's frag reads complete

        uint4 pk;
        pk.x = f2bf(a00.x) | ((unsigned)f2bf(a00.y) << 16);
        pk.y = f2bf(a00.z) | ((unsigned)f2bf(a00.w) << 16);
        pk.z = f2bf(a01.x) | ((unsigned)f2bf(a01.y) << 16);
        pk.w = f2bf(a01.z) | ((unsigned)f2bf(a01.w) << 16);
        *(uint4*)&As[r0][k8] = pk;
        pk.x = f2bf(a10.x) | ((unsigned)f2bf(a10.y) << 16);
        pk.y = f2bf(a10.z) | ((unsigned)f2bf(a10.w) << 16);
        pk.z = f2bf(a11.x) | ((unsigned)f2bf(a11.y) << 16);
        pk.w = f2bf(a11.z) | ((unsigned)f2bf(a11.w) << 16);
        *(uint4*)&As[r1][k8] = pk;
        pk.x = f2bf(b00.x) | ((unsigned)f2bf(b00.y) << 16);
        pk.y = f2bf(b00.z) | ((unsigned)f2bf(b00.w) << 16);
        pk.z = f2bf(b01.x) | ((unsigned)f2bf(b01.y) << 16);
        pk.w = f2bf(b01.z) | ((unsigned)f2bf(b01.w) << 16);
        *(uint4*)&Bs[r0][k8] = pk;
        pk.x = f2bf(b10.x) | ((unsigned)f2bf(b10.y) << 16);
        pk.y = f2bf(b10.z) | ((unsigned)f2bf(b10.w) << 16);
        pk.z = f2bf(b11.x) | ((unsigned)f2bf(b11.y) << 16);
        pk.w = f2bf(b11.z) | ((unsigned)f2bf(b11.w) << 16);
        *(uint4*)&Bs[r1][k8] = pk;

        __syncthreads();

        bf16x8 af[4], bfr[4];
#pragma unroll
        for (int mi = 0; mi < 4; ++mi)
            af[mi] = *(const bf16x8*)&As[wm + mi * 16 + tx][quad * 8];
#pragma unroll
        for (int ni = 0; ni < 4; ++ni)
            bfr[ni] = *(const bf16x8*)&Bs[wn + ni * 16 + tx][quad * 8];
#pragma unroll
        for (int mi = 0; mi < 4; ++mi)
#pragma unroll
            for (int ni = 0; ni < 4; ++ni)
                acc[mi][ni] = __builtin_amdgcn_mfma_f32_16x16x32_bf16(
                    af[mi], bfr[ni], acc[mi][ni], 0, 0, 0);
    }

    // epilogue: e = tanh(v + qpb + conv); partial score = sum_o s_w[o]*e
    float sacc[16];
#pragma unroll
    for (int i = 0; i < 16; ++i) sacc[i] = 0.f;

#pragma unroll
    for (int ni = 0; ni < 4; ++ni) {
        const int ol = wn + ni * 16 + tx;
        const float c0 = cw0s[ol], c1 = cw1s[ol], c2 = cw2s[ol];
        const float cb = cbs[ol], qp = qpbs[ol], sw = sws[ol];
#pragma unroll
        for (int mi = 0; mi < 4; ++mi)
#pragma unroll
            for (int r = 0; r < 4; ++r) {
                const int tl = wm + mi * 16 + quad * 4 + r;
                const float conv = c0 * las[tl] + c1 * las[tl + 1] + c2 * las[tl + 2] + cb;
                const float x = acc[mi][ni][r] + qp + conv;
                sacc[mi * 4 + r] += sw * fast_tanh(x);
            }
    }
#pragma unroll
    for (int i = 0; i < 16; ++i) {
        float v = sacc[i];
        v += __shfl_xor(v, 1);
        v += __shfl_xor(v, 2);
        v += __shfl_xor(v, 4);
        v += __shfl_xor(v, 8);
        if (tx == 0) {
            const int tl = wm + (i >> 2) * 16 + quad * 4 + (i & 3);
            atomicAdd(&pre[b * T + t0 + tl], v);
        }
    }
}

// ---------------- K3a: sigmoid + L1 normalize -> attn
__global__ __launch_bounds__(256) void k3a_norm(const float* __restrict__ pre,
                                                const float* __restrict__ s_b,
                                                float* __restrict__ attn_out) {
    const int b = blockIdx.x;
    const int tid = threadIdx.x;
    const float sb = s_b[0];
    float s[8];
    float loc = 0.f;
#pragma unroll
    for (int i = 0; i < 8; ++i) {
        const float p = pre[b * T + tid + i * 256] + sb;
        const float sg = 1.f / (1.f + expf(-p));
        s[i] = sg;
        loc += sg;
    }
    __shared__ float red[4];
#pragma unroll
    for (int m = 1; m < 64; m <<= 1) loc += __shfl_xor(loc, m);
    if ((tid & 63) == 0) red[tid >> 6] = loc;
    __syncthreads();
    const float inv = 1.f / (red[0] + red[1] + red[2] + red[3]);
#pragma unroll
    for (int i = 0; i < 8; ++i) attn_out[b * T + tid + i * 256] = s[i] * inv;
}

// ---------------- K3b: context = sum_t attn[t] * value[t,:]  (float4)
__global__ __launch_bounds__(256) void k3b_ctx(const float* __restrict__ value,
                                               const float* __restrict__ attn,
                                               float* __restrict__ ctx) {
    const int b = blockIdx.x;
    const int slice = blockIdx.y;   // 8 slices of 256 t
    const int tid = threadIdx.x;
    const int col = (tid & 127) * 4;
    const int tp = tid >> 7;        // 0,1
    const float* vb = value + (size_t)b * T * H;
    float4 a = {0.f, 0.f, 0.f, 0.f};
    const int tbeg = slice * 256;
    for (int t = tbeg + tp; t < tbeg + 256; t += 2) {
        const float w = attn[b * T + t];
        const float4 v = *(const float4*)(vb + (size_t)t * H + col);
        a.x += w * v.x; a.y += w * v.y; a.z += w * v.z; a.w += w * v.w;
    }
    atomicAdd(&ctx[b * H + col + 0], a.x);
    atomicAdd(&ctx[b * H + col + 1], a.y);
    atomicAdd(&ctx[b * H + col + 2], a.z);
    atomicAdd(&ctx[b * H + col + 3], a.w);
}

extern "C" void kernel_launch(void* const* d_in, const int* in_sizes, int n_in,
                              void* d_out, int out_size, void* d_ws, size_t ws_size,
                              hipStream_t stream) {
    const float* query  = (const float*)d_in[0];
    const float* value  = (const float*)d_in[1];
    const float* la     = (const float*)d_in[2];
    const float* conv_w = (const float*)d_in[3];
    const float* conv_b = (const float*)d_in[4];
    const float* q_w    = (const float*)d_in[5];
    const float* v_w    = (const float*)d_in[6];
    const float* s_w    = (const float*)d_in[7];
    const float* s_b    = (const float*)d_in[8];
    const float* bias   = (const float*)d_in[9];

    float* out  = (float*)d_out;
    float* ctx  = out;            // (B, H)
    float* attn = out + B * H;    // (B, T)

    float* qpb = (float*)d_ws;    // B*H
    float* pre = qpb + B * H;     // B*T

    k1_init<<<B, 256, 0, stream>>>(query, q_w, bias, qpb, pre, ctx);

    dim3 g2(T / BM, H / BN, B);
    k2_score_mfma<<<g2, 256, 0, stream>>>(value, v_w, la, conv_w, conv_b, s_w, qpb, pre);

    k3a_norm<<<B, 256, 0, stream>>>(pre, s_b, attn);

    dim3 g3(B, 8);
    k3b_ctx<<<g3, 256, 0, stream>>>(value, attn, ctx);
}

// Round 3
// 322.362 us; speedup vs baseline: 2.1931x; 1.1392x over previous
//
#include <hip/hip_runtime.h>
#include <math.h>

#define B 32
#define T 2048
#define H 512

#define BM 128
#define BN 128
// K chunk = 32

typedef __attribute__((ext_vector_type(8))) __bf16 bf16x8;
typedef __attribute__((ext_vector_type(4))) __bf16 bf16x4v;
typedef __attribute__((ext_vector_type(4))) float f32x4;
typedef __attribute__((ext_vector_type(4))) float floatx4;

union pack16 { bf16x4v h[2]; uint4 u; };

static __device__ __forceinline__ float fast_tanh(float x) {
    float ex = __expf(2.f * x);
    return 1.f - 2.f * __builtin_amdgcn_rcpf(ex + 1.f);
}

// ---------------- K1: q-projection GEMV + bias; zero pre and ctx
// grid (B, 8), block 256. Block handles 64 outputs of one batch.
__global__ __launch_bounds__(256) void k1_init(const float* __restrict__ query,
                                               const float* __restrict__ q_w,
                                               const float* __restrict__ bias,
                                               float* __restrict__ qpb,
                                               float* __restrict__ pre,
                                               float* __restrict__ ctx_out) {
    const int b = blockIdx.x;
    const int s = blockIdx.y;           // 0..7
    const int tid = threadIdx.x;
    const int wave = tid >> 6;
    const int lane = tid & 63;

    // zero pre (B*T) and ctx (B*H)
    pre[b * T + s * 256 + tid] = 0.f;
    if (s < 2) ctx_out[b * H + s * 256 + tid] = 0.f;

    // q fragment in registers: lane holds q[b, lane*8 .. lane*8+7]
    const float* qb = query + (size_t)b * H + lane * 8;
    float4 q0 = *(const float4*)qb;
    float4 q1 = *(const float4*)(qb + 4);

    const int o0 = s * 64 + wave * 16;
#pragma unroll
    for (int i = 0; i < 16; ++i) {
        const int o = o0 + i;
        const float* wr = q_w + (size_t)o * H + lane * 8;
        float4 w0 = *(const float4*)wr;
        float4 w1 = *(const float4*)(wr + 4);
        float acc = w0.x * q0.x + w0.y * q0.y + w0.z * q0.z + w0.w * q0.w +
                    w1.x * q1.x + w1.y * q1.y + w1.z * q1.z + w1.w * q1.w;
#pragma unroll
        for (int m = 1; m < 64; m <<= 1) acc += __shfl_xor(acc, m);
        if (lane == 0) qpb[b * H + o] = acc + bias[o];
    }
}

// ---------------- K2: bf16 MFMA v-projection + fused conv/tanh/score epilogue
__global__ __launch_bounds__(256) void k2_score_mfma(const float* __restrict__ value,
                                                     const float* __restrict__ v_w,
                                                     const float* __restrict__ la,
                                                     const float* __restrict__ conv_w,
                                                     const float* __restrict__ conv_b,
                                                     const float* __restrict__ s_w,
                                                     const float* __restrict__ qpb,
                                                     float* __restrict__ pre) {
    __shared__ unsigned short As[BM][40];   // padded stride: 40 bf16 = 80 B
    __shared__ unsigned short Bs[BN][40];
    __shared__ float qpbs[BN], sws[BN], cbs[BN], cw0s[BN], cw1s[BN], cw2s[BN];
    __shared__ float las[BM + 2];

    const int t0 = blockIdx.x * BM;
    const int o0 = blockIdx.y * BN;
    const int b  = blockIdx.z;
    const int tid = threadIdx.x;
    const int wave = tid >> 6;
    const int lane = tid & 63;
    const int tx   = lane & 15;
    const int quad = lane >> 4;
    const int wm = (wave >> 1) * 64;   // wave's t-offset within tile
    const int wn = (wave & 1) * 64;    // wave's o-offset within tile

    if (tid < BN) {
        const int o = o0 + tid;
        qpbs[tid] = qpb[b * H + o];
        sws[tid]  = s_w[o];
        cbs[tid]  = conv_b[o];
        cw0s[tid] = conv_w[o * 3 + 0];
        cw1s[tid] = conv_w[o * 3 + 1];
        cw2s[tid] = conv_w[o * 3 + 2];
    }
    if (tid < BM + 2) {
        const int t = t0 + tid - 1;
        las[tid] = (t >= 0 && t < T) ? la[b * T + t] : 0.f;
    }

    floatx4 acc[4][4];
#pragma unroll
    for (int i = 0; i < 4; ++i)
#pragma unroll
        for (int j = 0; j < 4; ++j) acc[i][j] = (floatx4){0.f, 0.f, 0.f, 0.f};

    const float* vbase = value + (size_t)b * T * H;

    const int r0 = tid >> 2;          // rows 0..63
    const int r1 = 64 + (tid >> 2);   // rows 64..127
    const int k8 = (tid & 3) * 8;

    for (int kc = 0; kc < H; kc += 32) {
        const float* ga0 = vbase + (size_t)(t0 + r0) * H + kc + k8;
        const float* ga1 = vbase + (size_t)(t0 + r1) * H + kc + k8;
        const float* gb0 = v_w + (size_t)(o0 + r0) * H + kc + k8;
        const float* gb1 = v_w + (size_t)(o0 + r1) * H + kc + k8;
        f32x4 a00 = *(const f32x4*)ga0, a01 = *(const f32x4*)(ga0 + 4);
        f32x4 a10 = *(const f32x4*)ga1, a11 = *(const f32x4*)(ga1 + 4);
        f32x4 b00 = *(const f32x4*)gb0, b01 = *(const f32x4*)(gb0 + 4);
        f32x4 b10 = *(const f32x4*)gb1, b11 = *(const f32x4*)(gb1 + 4);

        __syncthreads();   // previous iter's frag reads complete

        pack16 p;
        p.h[0] = __builtin_convertvector(a00, bf16x4v);
        p.h[1] = __builtin_convertvector(a01, bf16x4v);
        *(uint4*)&As[r0][k8] = p.u;
        p.h[0] = __builtin_convertvector(a10, bf16x4v);
        p.h[1] = __builtin_convertvector(a11, bf16x4v);
        *(uint4*)&As[r1][k8] = p.u;
        p.h[0] = __builtin_convertvector(b00, bf16x4v);
        p.h[1] = __builtin_convertvector(b01, bf16x4v);
        *(uint4*)&Bs[r0][k8] = p.u;
        p.h[0] = __builtin_convertvector(b10, bf16x4v);
        p.h[1] = __builtin_convertvector(b11, bf16x4v);
        *(uint4*)&Bs[r1][k8] = p.u;

        __syncthreads();

        bf16x8 af[4], bfr[4];
#pragma unroll
        for (int mi = 0; mi < 4; ++mi)
            af[mi] = *(const bf16x8*)&As[wm + mi * 16 + tx][quad * 8];
#pragma unroll
        for (int ni = 0; ni < 4; ++ni)
            bfr[ni] = *(const bf16x8*)&Bs[wn + ni * 16 + tx][quad * 8];
#pragma unroll
        for (int mi = 0; mi < 4; ++mi)
#pragma unroll
            for (int ni = 0; ni < 4; ++ni)
                acc[mi][ni] = __builtin_amdgcn_mfma_f32_16x16x32_bf16(
                    af[mi], bfr[ni], acc[mi][ni], 0, 0, 0);
    }

    // epilogue: e = tanh(v + qpb + conv); partial score = sum_o s_w[o]*e
    float sacc[16];
#pragma unroll
    for (int i = 0; i < 16; ++i) sacc[i] = 0.f;

#pragma unroll
    for (int ni = 0; ni < 4; ++ni) {
        const int ol = wn + ni * 16 + tx;
        const float c0 = cw0s[ol], c1 = cw1s[ol], c2 = cw2s[ol];
        const float cb = cbs[ol], qp = qpbs[ol], sw = sws[ol];
#pragma unroll
        for (int mi = 0; mi < 4; ++mi)
#pragma unroll
            for (int r = 0; r < 4; ++r) {
                const int tl = wm + mi * 16 + quad * 4 + r;
                const float conv = c0 * las[tl] + c1 * las[tl + 1] + c2 * las[tl + 2] + cb;
                const float x = acc[mi][ni][r] + qp + conv;
                sacc[mi * 4 + r] += sw * fast_tanh(x);
            }
    }
#pragma unroll
    for (int i = 0; i < 16; ++i) {
        float v = sacc[i];
        v += __shfl_xor(v, 1);
        v += __shfl_xor(v, 2);
        v += __shfl_xor(v, 4);
        v += __shfl_xor(v, 8);
        if (tx == 0) {
            const int tl = wm + (i >> 2) * 16 + quad * 4 + (i & 3);
            atomicAdd(&pre[b * T + t0 + tl], v);
        }
    }
}

// ---------------- K3a: sigmoid + L1 normalize -> attn
__global__ __launch_bounds__(256) void k3a_norm(const float* __restrict__ pre,
                                                const float* __restrict__ s_b,
                                                float* __restrict__ attn_out) {
    const int b = blockIdx.x;
    const int tid = threadIdx.x;
    const float sb = s_b[0];
    float s[8];
    float loc = 0.f;
#pragma unroll
    for (int i = 0; i < 8; ++i) {
        const float p = pre[b * T + tid + i * 256] + sb;
        const float sg = 1.f / (1.f + expf(-p));
        s[i] = sg;
        loc += sg;
    }
    __shared__ float red[4];
#pragma unroll
    for (int m = 1; m < 64; m <<= 1) loc += __shfl_xor(loc, m);
    if ((tid & 63) == 0) red[tid >> 6] = loc;
    __syncthreads();
    const float inv = 1.f / (red[0] + red[1] + red[2] + red[3]);
#pragma unroll
    for (int i = 0; i < 8; ++i) attn_out[b * T + tid + i * 256] = s[i] * inv;
}

// ---------------- K3b: context = sum_t attn[t] * value[t,:]  (float4, 16 slices)
__global__ __launch_bounds__(256) void k3b_ctx(const float* __restrict__ value,
                                               const float* __restrict__ attn,
                                               float* __restrict__ ctx) {
    const int b = blockIdx.x;
    const int slice = blockIdx.y;   // 16 slices of 128 t
    const int tid = threadIdx.x;
    const int col = (tid & 127) * 4;
    const int tp = tid >> 7;        // 0,1
    const float* vb = value + (size_t)b * T * H;
    float4 a = {0.f, 0.f, 0.f, 0.f};
    const int tbeg = slice * 128;
    for (int t = tbeg + tp; t < tbeg + 128; t += 2) {
        const float w = attn[b * T + t];
        const float4 v = *(const float4*)(vb + (size_t)t * H + col);
        a.x += w * v.x; a.y += w * v.y; a.z += w * v.z; a.w += w * v.w;
    }
    atomicAdd(&ctx[b * H + col + 0], a.x);
    atomicAdd(&ctx[b * H + col + 1], a.y);
    atomicAdd(&ctx[b * H + col + 2], a.z);
    atomicAdd(&ctx[b * H + col + 3], a.w);
}

extern "C" void kernel_launch(void* const* d_in, const int* in_sizes, int n_in,
                              void* d_out, int out_size, void* d_ws, size_t ws_size,
                              hipStream_t stream) {
    const float* query  = (const float*)d_in[0];
    const float* value  = (const float*)d_in[1];
    const float* la     = (const float*)d_in[2];
    const float* conv_w = (const float*)d_in[3];
    const float* conv_b = (const float*)d_in[4];
    const float* q_w    = (const float*)d_in[5];
    const float* v_w    = (const float*)d_in[6];
    const float* s_w    = (const float*)d_in[7];
    const float* s_b    = (const float*)d_in[8];
    const float* bias   = (const float*)d_in[9];

    float* out  = (float*)d_out;
    float* ctx  = out;            // (B, H)
    float* attn = out + B * H;    // (B, T)

    float* qpb = (float*)d_ws;    // B*H
    float* pre = qpb + B * H;     // B*T

    dim3 g1(B, 8);
    k1_init<<<g1, 256, 0, stream>>>(query, q_w, bias, qpb, pre, ctx);

    dim3 g2(T / BM, H / BN, B);
    k2_score_mfma<<<g2, 256, 0, stream>>>(value, v_w, la, conv_w, conv_b, s_w, qpb, pre);

    k3a_norm<<<B, 256, 0, stream>>>(pre, s_b, attn);

    dim3 g3(B, 16);
    k3b_ctx<<<g3, 256, 0, stream>>>(value, attn, ctx);
}

// Round 4
// 305.382 us; speedup vs baseline: 2.3150x; 1.0556x over previous
//
#include <hip/hip_runtime.h>
#include <math.h>

#define B 32
#define T 2048
#define H 512

#define BM 128
#define BN 128

typedef __attribute__((ext_vector_type(8))) __bf16 bf16x8;
typedef __attribute__((ext_vector_type(4))) __bf16 bf16x4v;
typedef __attribute__((ext_vector_type(4))) float f32x4;
typedef __attribute__((ext_vector_type(8))) float f32x8;
typedef __attribute__((ext_vector_type(4))) float floatx4;

union pack16 { bf16x4v h[2]; uint4 u; };
union pack8  { bf16x4v h; uint2 u; };

static __device__ __forceinline__ float fast_tanh(float x) {
    float ex = __expf(2.f * x);
    return 1.f - 2.f * __builtin_amdgcn_rcpf(ex + 1.f);
}

static __device__ __forceinline__ void gl_lds16(const void* g, void* l) {
    __builtin_amdgcn_global_load_lds(
        (const __attribute__((address_space(1))) void*)g,
        (__attribute__((address_space(3))) void*)l, 16, 0, 0);
}

// ---------------- K0: convert value (B*T*H) and v_w (H*H) fp32 -> bf16 in ws
// grid: 8192 blocks for value + 64 for v_w; 256 thr; 16 elems/thread, coalesced sweeps
__global__ __launch_bounds__(256) void k0_convert(const float* __restrict__ value,
                                                  const float* __restrict__ v_w,
                                                  unsigned short* __restrict__ vbf,
                                                  unsigned short* __restrict__ wbf) {
    const int blk = blockIdx.x;
    const int tid = threadIdx.x;
    const float* src;
    unsigned short* dst;
    size_t base;
    if (blk < 8192) { src = value; dst = vbf; base = (size_t)blk * 4096; }
    else            { src = v_w;   dst = wbf; base = (size_t)(blk - 8192) * 4096; }
#pragma unroll
    for (int s = 0; s < 4; ++s) {
        const size_t off = base + s * 1024 + tid * 4;
        f32x4 a = *(const f32x4*)(src + off);
        pack8 p;
        p.h = __builtin_convertvector(a, bf16x4v);
        *(uint2*)(dst + off) = p.u;
    }
}

// ---------------- K1: q-projection GEMV + bias; zero pre and ctx
__global__ __launch_bounds__(256) void k1_init(const float* __restrict__ query,
                                               const float* __restrict__ q_w,
                                               const float* __restrict__ bias,
                                               float* __restrict__ qpb,
                                               float* __restrict__ pre,
                                               float* __restrict__ ctx_out) {
    const int b = blockIdx.x;
    const int s = blockIdx.y;           // 0..7
    const int tid = threadIdx.x;
    const int wave = tid >> 6;
    const int lane = tid & 63;

    pre[b * T + s * 256 + tid] = 0.f;
    if (s < 2) ctx_out[b * H + s * 256 + tid] = 0.f;

    const float* qb = query + (size_t)b * H + lane * 8;
    float4 q0 = *(const float4*)qb;
    float4 q1 = *(const float4*)(qb + 4);

    const int o0 = s * 64 + wave * 16;
#pragma unroll
    for (int i = 0; i < 16; ++i) {
        const int o = o0 + i;
        const float* wr = q_w + (size_t)o * H + lane * 8;
        float4 w0 = *(const float4*)wr;
        float4 w1 = *(const float4*)(wr + 4);
        float acc = w0.x * q0.x + w0.y * q0.y + w0.z * q0.z + w0.w * q0.w +
                    w1.x * q1.x + w1.y * q1.y + w1.z * q1.z + w1.w * q1.w;
#pragma unroll
        for (int m = 1; m < 64; m <<= 1) acc += __shfl_xor(acc, m);
        if (lane == 0) qpb[b * H + o] = acc + bias[o];
    }
}

// ---------------- K2 fast: bf16 MFMA with global_load_lds staging
__global__ __launch_bounds__(256) void k2_score_bf(const unsigned short* __restrict__ vbf,
                                                   const unsigned short* __restrict__ wbf,
                                                   const float* __restrict__ la,
                                                   const float* __restrict__ conv_w,
                                                   const float* __restrict__ conv_b,
                                                   const float* __restrict__ s_w,
                                                   const float* __restrict__ qpb,
                                                   float* __restrict__ pre) {
    __shared__ __align__(16) unsigned short As[BM * 32];   // 8 KB, row-major [128][32]
    __shared__ __align__(16) unsigned short Bs[BN * 32];   // 8 KB
    __shared__ float qpbs[BN], sws[BN], cbs[BN], cw0s[BN], cw1s[BN], cw2s[BN];
    __shared__ float las[BM + 2];

    const int t0 = blockIdx.x * BM;
    const int o0 = blockIdx.y * BN;
    const int b  = blockIdx.z;
    const int tid = threadIdx.x;
    const int wave = tid >> 6;
    const int lane = tid & 63;
    const int tx   = lane & 15;
    const int quad = lane >> 4;
    const int wm = (wave >> 1) * 64;
    const int wn = (wave & 1) * 64;

    if (tid < BN) {
        const int o = o0 + tid;
        qpbs[tid] = qpb[b * H + o];
        sws[tid]  = s_w[o];
        cbs[tid]  = conv_b[o];
        cw0s[tid] = conv_w[o * 3 + 0];
        cw1s[tid] = conv_w[o * 3 + 1];
        cw2s[tid] = conv_w[o * 3 + 2];
    }
    if (tid < BM + 2) {
        const int t = t0 + tid - 1;
        las[tid] = (t >= 0 && t < T) ? la[b * T + t] : 0.f;
    }

    floatx4 acc[4][4];
#pragma unroll
    for (int i = 0; i < 4; ++i)
#pragma unroll
        for (int j = 0; j < 4; ++j) acc[i][j] = (floatx4){0.f, 0.f, 0.f, 0.f};

    // staging: wave w stages 1-KB chunks {w, w+4} of A and of B.
    // chunk c covers rows [c*16, c*16+16); lane l -> row c*16 + (l>>2), col (l&3)*8
    const int rA = lane >> 2;
    const int ck = (lane & 3) * 8;
    const unsigned short* gA0 = vbf + ((size_t)b * T + t0 + wave * 16 + rA) * H + ck;
    const unsigned short* gA1 = gA0 + (size_t)64 * H;
    const unsigned short* gB0 = wbf + (size_t)(o0 + wave * 16 + rA) * H + ck;
    const unsigned short* gB1 = gB0 + (size_t)64 * H;
    unsigned short* lA0 = &As[wave * 512];
    unsigned short* lA1 = &As[(wave + 4) * 512];
    unsigned short* lB0 = &Bs[wave * 512];
    unsigned short* lB1 = &Bs[(wave + 4) * 512];

    for (int kc = 0; kc < H; kc += 32) {
        __syncthreads();               // prior frag reads complete before overwrite
        gl_lds16(gA0, lA0);
        gl_lds16(gA1, lA1);
        gl_lds16(gB0, lB0);
        gl_lds16(gB1, lB1);
        gA0 += 32; gA1 += 32; gB0 += 32; gB1 += 32;
        __syncthreads();               // drains vmcnt -> LDS visible

        bf16x8 af[4], bfr[4];
#pragma unroll
        for (int mi = 0; mi < 4; ++mi)
            af[mi] = *(const bf16x8*)&As[(wm + mi * 16 + tx) * 32 + quad * 8];
#pragma unroll
        for (int ni = 0; ni < 4; ++ni)
            bfr[ni] = *(const bf16x8*)&Bs[(wn + ni * 16 + tx) * 32 + quad * 8];
#pragma unroll
        for (int mi = 0; mi < 4; ++mi)
#pragma unroll
            for (int ni = 0; ni < 4; ++ni)
                acc[mi][ni] = __builtin_amdgcn_mfma_f32_16x16x32_bf16(
                    af[mi], bfr[ni], acc[mi][ni], 0, 0, 0);
    }

    float sacc[16];
#pragma unroll
    for (int i = 0; i < 16; ++i) sacc[i] = 0.f;

#pragma unroll
    for (int ni = 0; ni < 4; ++ni) {
        const int ol = wn + ni * 16 + tx;
        const float c0 = cw0s[ol], c1 = cw1s[ol], c2 = cw2s[ol];
        const float cb = cbs[ol], qp = qpbs[ol], sw = sws[ol];
#pragma unroll
        for (int mi = 0; mi < 4; ++mi)
#pragma unroll
            for (int r = 0; r < 4; ++r) {
                const int tl = wm + mi * 16 + quad * 4 + r;
                const float conv = c0 * las[tl] + c1 * las[tl + 1] + c2 * las[tl + 2] + cb;
                const float x = acc[mi][ni][r] + qp + conv;
                sacc[mi * 4 + r] += sw * fast_tanh(x);
            }
    }
#pragma unroll
    for (int i = 0; i < 16; ++i) {
        float v = sacc[i];
        v += __shfl_xor(v, 1);
        v += __shfl_xor(v, 2);
        v += __shfl_xor(v, 4);
        v += __shfl_xor(v, 8);
        if (tx == 0) {
            const int tl = wm + (i >> 2) * 16 + quad * 4 + (i & 3);
            atomicAdd(&pre[b * T + t0 + tl], v);
        }
    }
}

// ---------------- K3 fused: sigmoid + normalize + attn write + context (bf16 value)
__global__ __launch_bounds__(256) void k3_fused(const unsigned short* __restrict__ vbf,
                                                const float* __restrict__ pre,
                                                const float* __restrict__ s_b,
                                                float* __restrict__ attn_out,
                                                float* __restrict__ ctx) {
    __shared__ float sm[T];          // 8 KB
    __shared__ float red[4];
    __shared__ float redc[4][H];     // 8 KB
    const int b = blockIdx.x;
    const int slice = blockIdx.y;    // 0..15, each 128 t
    const int tid = threadIdx.x;
    const float sb = s_b[0];

    float s[8];
    float loc = 0.f;
#pragma unroll
    for (int i = 0; i < 8; ++i) {
        const float p = pre[b * T + tid + i * 256] + sb;
        const float sg = 1.f / (1.f + expf(-p));
        s[i] = sg;
        sm[tid + i * 256] = sg;
        loc += sg;
    }
#pragma unroll
    for (int m = 1; m < 64; m <<= 1) loc += __shfl_xor(loc, m);
    if ((tid & 63) == 0) red[tid >> 6] = loc;
    __syncthreads();
    const float inv = 1.f / (red[0] + red[1] + red[2] + red[3]);
    if (slice == 0) {
#pragma unroll
        for (int i = 0; i < 8; ++i) attn_out[b * T + tid + i * 256] = s[i] * inv;
    }

    // context slice: cols (tid&63)*8, t-phase tid>>6
    const int col = (tid & 63) * 8;
    const int tp  = tid >> 6;
    f32x8 a;
#pragma unroll
    for (int i = 0; i < 8; ++i) a[i] = 0.f;
    const unsigned short* vb = vbf + ((size_t)b * T) * H + col;
    const int tbeg = slice * 128;
    for (int t = tbeg + tp; t < tbeg + 128; t += 4) {
        const float w = sm[t] * inv;
        bf16x8 v = *(const bf16x8*)(vb + (size_t)t * H);
        f32x8 vf = __builtin_convertvector(v, f32x8);
#pragma unroll
        for (int i = 0; i < 8; ++i) a[i] += w * vf[i];
    }
    *(f32x4*)&redc[tp][col]     = (f32x4){a[0], a[1], a[2], a[3]};
    *(f32x4*)&redc[tp][col + 4] = (f32x4){a[4], a[5], a[6], a[7]};
    __syncthreads();
    if (tid < 128) {
        const int h = tid * 4;
        f32x4 r0 = *(const f32x4*)&redc[0][h];
        f32x4 r1 = *(const f32x4*)&redc[1][h];
        f32x4 r2 = *(const f32x4*)&redc[2][h];
        f32x4 r3 = *(const f32x4*)&redc[3][h];
        atomicAdd(&ctx[b * H + h + 0], r0[0] + r1[0] + r2[0] + r3[0]);
        atomicAdd(&ctx[b * H + h + 1], r0[1] + r1[1] + r2[1] + r3[1]);
        atomicAdd(&ctx[b * H + h + 2], r0[2] + r1[2] + r2[2] + r3[2]);
        atomicAdd(&ctx[b * H + h + 3], r0[3] + r1[3] + r2[3] + r3[3]);
    }
}

// ================= fallback path (ws too small): round-3 kernels =================
__global__ __launch_bounds__(256) void k2_fb(const float* __restrict__ value,
                                             const float* __restrict__ v_w,
                                             const float* __restrict__ la,
                                             const float* __restrict__ conv_w,
                                             const float* __restrict__ conv_b,
                                             const float* __restrict__ s_w,
                                             const float* __restrict__ qpb,
                                             float* __restrict__ pre) {
    __shared__ unsigned short As[BM][40];
    __shared__ unsigned short Bs[BN][40];
    __shared__ float qpbs[BN], sws[BN], cbs[BN], cw0s[BN], cw1s[BN], cw2s[BN];
    __shared__ float las[BM + 2];

    const int t0 = blockIdx.x * BM;
    const int o0 = blockIdx.y * BN;
    const int b  = blockIdx.z;
    const int tid = threadIdx.x;
    const int wave = tid >> 6;
    const int lane = tid & 63;
    const int tx   = lane & 15;
    const int quad = lane >> 4;
    const int wm = (wave >> 1) * 64;
    const int wn = (wave & 1) * 64;

    if (tid < BN) {
        const int o = o0 + tid;
        qpbs[tid] = qpb[b * H + o];
        sws[tid]  = s_w[o];
        cbs[tid]  = conv_b[o];
        cw0s[tid] = conv_w[o * 3 + 0];
        cw1s[tid] = conv_w[o * 3 + 1];
        cw2s[tid] = conv_w[o * 3 + 2];
    }
    if (tid < BM + 2) {
        const int t = t0 + tid - 1;
        las[tid] = (t >= 0 && t < T) ? la[b * T + t] : 0.f;
    }

    floatx4 acc[4][4];
#pragma unroll
    for (int i = 0; i < 4; ++i)
#pragma unroll
        for (int j = 0; j < 4; ++j) acc[i][j] = (floatx4){0.f, 0.f, 0.f, 0.f};

    const float* vbase = value + (size_t)b * T * H;
    const int r0 = tid >> 2;
    const int r1 = 64 + (tid >> 2);
    const int k8 = (tid & 3) * 8;

    for (int kc = 0; kc < H; kc += 32) {
        const float* ga0 = vbase + (size_t)(t0 + r0) * H + kc + k8;
        const float* ga1 = vbase + (size_t)(t0 + r1) * H + kc + k8;
        const float* gb0 = v_w + (size_t)(o0 + r0) * H + kc + k8;
        const float* gb1 = v_w + (size_t)(o0 + r1) * H + kc + k8;
        f32x4 a00 = *(const f32x4*)ga0, a01 = *(const f32x4*)(ga0 + 4);
        f32x4 a10 = *(const f32x4*)ga1, a11 = *(const f32x4*)(ga1 + 4);
        f32x4 b00 = *(const f32x4*)gb0, b01 = *(const f32x4*)(gb0 + 4);
        f32x4 b10 = *(const f32x4*)gb1, b11 = *(const f32x4*)(gb1 + 4);

        __syncthreads();

        pack16 p;
        p.h[0] = __builtin_convertvector(a00, bf16x4v);
        p.h[1] = __builtin_convertvector(a01, bf16x4v);
        *(uint4*)&As[r0][k8] = p.u;
        p.h[0] = __builtin_convertvector(a10, bf16x4v);
        p.h[1] = __builtin_convertvector(a11, bf16x4v);
        *(uint4*)&As[r1][k8] = p.u;
        p.h[0] = __builtin_convertvector(b00, bf16x4v);
        p.h[1] = __builtin_convertvector(b01, bf16x4v);
        *(uint4*)&Bs[r0][k8] = p.u;
        p.h[0] = __builtin_convertvector(b10, bf16x4v);
        p.h[1] = __builtin_convertvector(b11, bf16x4v);
        *(uint4*)&Bs[r1][k8] = p.u;

        __syncthreads();

        bf16x8 af[4], bfr[4];
#pragma unroll
        for (int mi = 0; mi < 4; ++mi)
            af[mi] = *(const bf16x8*)&As[wm + mi * 16 + tx][quad * 8];
#pragma unroll
        for (int ni = 0; ni < 4; ++ni)
            bfr[ni] = *(const bf16x8*)&Bs[wn + ni * 16 + tx][quad * 8];
#pragma unroll
        for (int mi = 0; mi < 4; ++mi)
#pragma unroll
            for (int ni = 0; ni < 4; ++ni)
                acc[mi][ni] = __builtin_amdgcn_mfma_f32_16x16x32_bf16(
                    af[mi], bfr[ni], acc[mi][ni], 0, 0, 0);
    }

    float sacc[16];
#pragma unroll
    for (int i = 0; i < 16; ++i) sacc[i] = 0.f;
#pragma unroll
    for (int ni = 0; ni < 4; ++ni) {
        const int ol = wn + ni * 16 + tx;
        const float c0 = cw0s[ol], c1 = cw1s[ol], c2 = cw2s[ol];
        const float cb = cbs[ol], qp = qpbs[ol], sw = sws[ol];
#pragma unroll
        for (int mi = 0; mi < 4; ++mi)
#pragma unroll
            for (int r = 0; r < 4; ++r) {
                const int tl = wm + mi * 16 + quad * 4 + r;
                const float conv = c0 * las[tl] + c1 * las[tl + 1] + c2 * las[tl + 2] + cb;
                const float x = acc[mi][ni][r] + qp + conv;
                sacc[mi * 4 + r] += sw * fast_tanh(x);
            }
    }
#pragma unroll
    for (int i = 0; i < 16; ++i) {
        float v = sacc[i];
        v += __shfl_xor(v, 1);
        v += __shfl_xor(v, 2);
        v += __shfl_xor(v, 4);
        v += __shfl_xor(v, 8);
        if (tx == 0) {
            const int tl = wm + (i >> 2) * 16 + quad * 4 + (i & 3);
            atomicAdd(&pre[b * T + t0 + tl], v);
        }
    }
}

__global__ __launch_bounds__(256) void k3a_fb(const float* __restrict__ pre,
                                              const float* __restrict__ s_b,
                                              float* __restrict__ attn_out) {
    const int b = blockIdx.x;
    const int tid = threadIdx.x;
    const float sb = s_b[0];
    float s[8];
    float loc = 0.f;
#pragma unroll
    for (int i = 0; i < 8; ++i) {
        const float p = pre[b * T + tid + i * 256] + sb;
        const float sg = 1.f / (1.f + expf(-p));
        s[i] = sg;
        loc += sg;
    }
    __shared__ float red[4];
#pragma unroll
    for (int m = 1; m < 64; m <<= 1) loc += __shfl_xor(loc, m);
    if ((tid & 63) == 0) red[tid >> 6] = loc;
    __syncthreads();
    const float inv = 1.f / (red[0] + red[1] + red[2] + red[3]);
#pragma unroll
    for (int i = 0; i < 8; ++i) attn_out[b * T + tid + i * 256] = s[i] * inv;
}

__global__ __launch_bounds__(256) void k3b_fb(const float* __restrict__ value,
                                              const float* __restrict__ attn,
                                              float* __restrict__ ctx) {
    const int b = blockIdx.x;
    const int slice = blockIdx.y;
    const int tid = threadIdx.x;
    const int col = (tid & 127) * 4;
    const int tp = tid >> 7;
    const float* vb = value + (size_t)b * T * H;
    float4 a = {0.f, 0.f, 0.f, 0.f};
    const int tbeg = slice * 128;
    for (int t = tbeg + tp; t < tbeg + 128; t += 2) {
        const float w = attn[b * T + t];
        const float4 v = *(const float4*)(vb + (size_t)t * H + col);
        a.x += w * v.x; a.y += w * v.y; a.z += w * v.z; a.w += w * v.w;
    }
    atomicAdd(&ctx[b * H + col + 0], a.x);
    atomicAdd(&ctx[b * H + col + 1], a.y);
    atomicAdd(&ctx[b * H + col + 2], a.z);
    atomicAdd(&ctx[b * H + col + 3], a.w);
}

extern "C" void kernel_launch(void* const* d_in, const int* in_sizes, int n_in,
                              void* d_out, int out_size, void* d_ws, size_t ws_size,
                              hipStream_t stream) {
    const float* query  = (const float*)d_in[0];
    const float* value  = (const float*)d_in[1];
    const float* la     = (const float*)d_in[2];
    const float* conv_w = (const float*)d_in[3];
    const float* conv_b = (const float*)d_in[4];
    const float* q_w    = (const float*)d_in[5];
    const float* v_w    = (const float*)d_in[6];
    const float* s_w    = (const float*)d_in[7];
    const float* s_b    = (const float*)d_in[8];
    const float* bias   = (const float*)d_in[9];

    float* out  = (float*)d_out;
    float* ctx  = out;            // (B, H)
    float* attn = out + B * H;    // (B, T)

    float* qpb = (float*)d_ws;    // B*H floats
    float* pre = qpb + B * H;     // B*T floats
    unsigned short* wbf = (unsigned short*)(pre + B * T);      // H*H bf16
    unsigned short* vbf = wbf + (size_t)H * H;                 // B*T*H bf16

    const size_t needed = (size_t)(B * H + B * T) * 4 + (size_t)H * H * 2
                        + (size_t)B * T * H * 2;

    dim3 g1(B, 8);
    dim3 g2(T / BM, H / BN, B);

    if (ws_size >= needed) {
        k0_convert<<<8192 + 64, 256, 0, stream>>>(value, v_w, vbf, wbf);
        k1_init<<<g1, 256, 0, stream>>>(query, q_w, bias, qpb, pre, ctx);
        k2_score_bf<<<g2, 256, 0, stream>>>(vbf, wbf, la, conv_w, conv_b, s_w, qpb, pre);
        dim3 g3(B, 16);
        k3_fused<<<g3, 256, 0, stream>>>(vbf, pre, s_b, attn, ctx);
    } else {
        k1_init<<<g1, 256, 0, stream>>>(query, q_w, bias, qpb, pre, ctx);
        k2_fb<<<g2, 256, 0, stream>>>(value, v_w, la, conv_w, conv_b, s_w, qpb, pre);
        k3a_fb<<<B, 256, 0, stream>>>(pre, s_b, attn);
        dim3 g3(B, 16);
        k3b_fb<<<g3, 256, 0, stream>>>(value, attn, ctx);
    }
}